// Round 6
// baseline (480.673 us; speedup 1.0000x reference)
//
#include <hip/hip_runtime.h>
#include <math.h>

#define B_ 32
#define L_ 512
#define D_ 512
#define S_ 8

using f16x8 = __attribute__((ext_vector_type(8))) _Float16;
using f32x4 = __attribute__((ext_vector_type(4))) float;

__device__ __forceinline__ float sigm(float x) { return 1.0f / (1.0f + __expf(-x)); }

__device__ __forceinline__ void stage16(const _Float16* g, _Float16* l) {
    __builtin_amdgcn_global_load_lds(
        (const __attribute__((address_space(1))) void*)g,
        (__attribute__((address_space(3))) void*)l, 16, 0, 0);
}

// ---------------------------------------------------------------------------
// fp32 rows -> tiled fp16 [rtile][kt16][kq4][row128][8].  Block = (rtile, kt-quarter).
// ---------------------------------------------------------------------------
__global__ __launch_bounds__(256) void conv_tiled_kernel(
    const float* __restrict__ in, _Float16* __restrict__ outh)
{
    __shared__ __align__(16) float scr[4096];     // [kq4][row128][8]
    const int t = threadIdx.x;
    const int rt = blockIdx.x & 127;
    const int kt0 = (blockIdx.x >> 7) * 4;
    const size_t base_in  = (size_t)rt * 128 * D_;
    const size_t base_out = (size_t)rt * 65536;
    for (int kt = kt0; kt < kt0 + 4; ++kt) {
        if (kt != kt0) __syncthreads();
        #pragma unroll
        for (int f = 0; f < 4; ++f) {
            const int fi = t + f * 256;            // 0..1023
            const int row = fi >> 3, c4 = fi & 7;
            float4 v = *(const float4*)(in + base_in + (size_t)row * D_ + kt * 32 + c4 * 4);
            *(float4*)(scr + ((c4 >> 1) * 128 + row) * 8 + (c4 & 1) * 4) = v;
        }
        __syncthreads();
        #pragma unroll
        for (int c = 0; c < 2; ++c) {
            const int s = t + c * 256;             // 0..511
            const float4 v0 = *(const float4*)(scr + s * 8);
            const float4 v1 = *(const float4*)(scr + s * 8 + 4);
            const float vv[8] = {v0.x, v0.y, v0.z, v0.w, v1.x, v1.y, v1.z, v1.w};
            f16x8 h;
            #pragma unroll
            for (int i = 0; i < 8; ++i) h[i] = (_Float16)vv[i];
            *(f16x8*)(outh + base_out + kt * 4096 + s * 8) = h;
        }
    }
}

// ---------------------------------------------------------------------------
// Mr [k][d][e] fp32 -> fp16 tiled over n=k*512+e: [ntile][kt_d][kq][n128][8d]
// ---------------------------------------------------------------------------
__global__ __launch_bounds__(256) void conv_mrT_kernel(
    const float* __restrict__ Mr, _Float16* __restrict__ out)
{
    __shared__ float tile[32][33];
    const int k = blockIdx.z;
    const int e0 = blockIdx.x * 32, d0 = blockIdx.y * 32;
    const int tx = threadIdx.x & 31, ty = threadIdx.x >> 5;
    #pragma unroll
    for (int i = 0; i < 4; ++i) {
        const int dl = ty + i * 8;
        tile[dl][tx] = Mr[(size_t)k * (D_ * D_) + (size_t)(d0 + dl) * D_ + e0 + tx];
    }
    __syncthreads();
    if (threadIdx.x < 128) {
        const int el = threadIdx.x & 31, dc = threadIdx.x >> 5;   // dc 0..3
        f16x8 h;
        #pragma unroll
        for (int i = 0; i < 8; ++i) h[i] = (_Float16)tile[dc * 8 + i][el];
        const int e = e0 + el, d = d0 + dc * 8;
        const size_t addr = (size_t)(k * 4 + (e >> 7)) * 65536
                          + (size_t)(d >> 5) * 4096 + ((d >> 3) & 3) * 1024
                          + (size_t)(e & 127) * 8;
        *(f16x8*)(out + addr) = h;
    }
}

// ---------------------------------------------------------------------------
// Pack Wg/V -> Wt[side][kt][q][n16][j8] fp16, element = W'side[d=kt*32+q*8+j][n]
// ---------------------------------------------------------------------------
__global__ __launch_bounds__(256) void convW_kernel(
    const float* __restrict__ Wg, const float* __restrict__ V,
    _Float16* __restrict__ Wt)
{
    const int idx = blockIdx.x * 256 + threadIdx.x;    // 0..16383
    const int j = idx & 7;
    const int n = (idx >> 3) & 15;
    const int q = (idx >> 7) & 3;
    const int kt = (idx >> 9) & 15;
    const int side = idx >> 13;
    const int d = side * 512 + kt * 32 + q * 8 + j;
    const float v = (n < 8) ? Wg[d * S_ + n] : V[d * S_ + (n - 8)];
    Wt[idx] = (_Float16)v;
}

// ---------------------------------------------------------------------------
// MFMA projections: side0: [G1|S1] = a1 @ W'0 (+Bg on G1); side1: [G2|S2].
// ---------------------------------------------------------------------------
__global__ __launch_bounds__(256) void proj_mfma_kernel(
    const _Float16* __restrict__ a1h, const _Float16* __restrict__ a2h,
    const _Float16* __restrict__ Wt, const float* __restrict__ Bg,
    float* __restrict__ G1, float* __restrict__ G2,
    float* __restrict__ S1, float* __restrict__ S2)
{
    const int t = threadIdx.x;
    const int lane = t & 63, wv = t >> 6;
    const int q = lane >> 4, i15 = lane & 15;
    const int id = blockIdx.x;
    const int side = id >> 8;                  // 0..1
    const int rb = id & 255;                   // 64-row group
    const int rtile = rb >> 1;
    const int rbase = (rb & 1) * 64 + wv * 16; // row base within rtile

    const _Float16* A = (side ? a2h : a1h) + (size_t)rtile * 65536;
    const _Float16* W = Wt + side * 8192;

    f32x4 acc = {0.f, 0.f, 0.f, 0.f};
    #pragma unroll
    for (int kt = 0; kt < 16; ++kt) {
        f16x8 a = *(const f16x8*)(A + (size_t)kt * 4096 + q * 1024 + (rbase + i15) * 8);
        f16x8 b = *(const f16x8*)(W + (size_t)(kt * 4 + q) * 128 + i15 * 8);
        acc = __builtin_amdgcn_mfma_f32_16x16x32_f16(a, b, acc, 0, 0, 0);
    }

    float* dst = (i15 < 8) ? (side ? G2 : G1) : (side ? S2 : S1);
    const int n = i15 & 7;
    const float add = (side == 0 && i15 < 8) ? Bg[n] : 0.f;
    const int R0 = rtile * 128 + rbase + q * 4;
    #pragma unroll
    for (int r = 0; r < 4; ++r)
        dst[(size_t)(R0 + r) * S_ + n] = acc[r] + add;
}

// ---------------------------------------------------------------------------
// GEMM A: A1 = a1 @ Mr (single fp16). Single-buffer 32 KB LDS, BK=64,
// __launch_bounds__(256,4) -> target 4 blocks/CU for wave-level overlap.
// Output A1 fp16, tiled [itile][kt_e][kq_e][m=k*16+i15][8e], chunk-local.
// ---------------------------------------------------------------------------
__global__ __launch_bounds__(256, 4) void gemm_a_kernel(
    const _Float16* __restrict__ Ah, const _Float16* __restrict__ Bt,
    _Float16* __restrict__ C, int ytile0, int nY)
{
    __shared__ __align__(16) _Float16 lds[16384];   // 32 KB: As 16KB + Bs 16KB
    _Float16* As = lds;
    _Float16* Bs = lds + 8192;

    const int t = threadIdx.x;
    const int lane = t & 63, wv = t >> 6;
    const int wm = wv >> 1, wn = wv & 1;
    const int q = lane >> 4, i15 = lane & 15;

    int nt, yl;
    {
        const int id = blockIdx.x;
        if (nY >= 8) { const int y0 = id & 7; const int r = id >> 3; nt = r & 31; yl = (r >> 5) * 8 + y0; }
        else         { nt = id & 31; yl = id >> 5; }
    }
    const size_t abase = (size_t)(ytile0 + yl) * 65536;
    const size_t bbase = (size_t)nt * 65536;
    const int kblk = nt >> 2;
    const int e0 = (nt & 3) * 128;
    const int r0 = yl * 128;

    f32x4 acc[4][4];
    const f32x4 zero = {0.f, 0.f, 0.f, 0.f};
    #pragma unroll
    for (int a = 0; a < 4; ++a)
        #pragma unroll
        for (int b = 0; b < 4; ++b) acc[a][b] = zero;

    for (int kt2 = 0; kt2 < 8; ++kt2) {
        const size_t ab = abase + kt2 * 8192;
        const size_t bb = bbase + kt2 * 8192;
        #pragma unroll
        for (int c = 0; c < 4; ++c) {
            const int s8 = t + c * 256;
            stage16(Ah + ab + s8 * 8, As + s8 * 8);
            stage16(Bt + bb + s8 * 8, Bs + s8 * 8);
        }
        __syncthreads();
        #pragma unroll
        for (int kk2 = 0; kk2 < 2; ++kk2) {
            const int kq = kk2 * 4 + q;
            f16x8 bfr[4];
            #pragma unroll
            for (int nn = 0; nn < 4; ++nn)
                bfr[nn] = *(const f16x8*)(Bs + ((size_t)kq * 128 + wn * 64 + nn * 16 + i15) * 8);
            #pragma unroll
            for (int mt = 0; mt < 4; ++mt) {
                const int m = wm * 64 + mt * 16 + i15;
                f16x8 a = *(const f16x8*)(As + ((size_t)kq * 128 + m) * 8);
                #pragma unroll
                for (int nn = 0; nn < 4; ++nn)
                    acc[mt][nn] = __builtin_amdgcn_mfma_f32_16x16x32_f16(a, bfr[nn], acc[mt][nn], 0, 0, 0);
            }
        }
        __syncthreads();
    }

    // epilogue: per-wave LDS transpose -> tiled fp16 A1, 256B-contiguous stores
    float* scr = (float*)lds + wv * 1104;           // 16 x 68 floats
    #pragma unroll
    for (int mt = 0; mt < 4; ++mt) {
        #pragma unroll
        for (int nn = 0; nn < 4; ++nn)
            #pragma unroll
            for (int r = 0; r < 4; ++r)
                scr[(q * 4 + r) * 68 + nn * 16 + i15] = acc[mt][nn][r];
        __builtin_amdgcn_s_waitcnt(0);
        #pragma unroll
        for (int cc = 0; cc < 2; ++cc) {
            const int row = lane & 15;
            const int ech = (lane >> 4) + cc * 4;   // 0..7
            const float4 v0 = *(const float4*)(scr + row * 68 + ech * 8);
            const float4 v1 = *(const float4*)(scr + row * 68 + ech * 8 + 4);
            const float vv[8] = {v0.x, v0.y, v0.z, v0.w, v1.x, v1.y, v1.z, v1.w};
            f16x8 h;
            #pragma unroll
            for (int i = 0; i < 8; ++i) h[i] = (_Float16)vv[i];
            const int e = e0 + wn * 64 + ech * 8;
            const int ig = r0 + wm * 64 + mt * 16 + row;
            const size_t addr = (size_t)(ig >> 4) * 65536
                              + (size_t)(e >> 5) * 4096 + ((e >> 3) & 3) * 1024
                              + (size_t)(kblk * 16 + row) * 8;
            *(f16x8*)(C + addr) = h;
        }
        __builtin_amdgcn_s_waitcnt(0);
    }
}

// ---------------------------------------------------------------------------
// GEMM B + fused epilogue. Single-buffer 32 KB LDS, BK=64, (256,4).
// Swizzled grid: all blocks of one batch share an XCD (a2/A1 L2-resident).
// ---------------------------------------------------------------------------
__global__ __launch_bounds__(256, 4) void gemm_b_kernel(
    const _Float16* __restrict__ A1, const _Float16* __restrict__ a2t,
    const float* __restrict__ G1, const float* __restrict__ G2,
    const float* __restrict__ S1, const float* __restrict__ S2,
    const float* __restrict__ U, const float* __restrict__ bvec,
    float* __restrict__ out, int b0, int NB)
{
    __shared__ __align__(16) _Float16 lds[16384];   // 32 KB
    _Float16* As = lds;
    _Float16* Bs = lds + 8192;

    const int t = threadIdx.x;
    const int lane = t & 63, wv = t >> 6;
    const int wm = wv >> 1, wn = wv & 1;
    const int q = lane >> 4, i15 = lane & 15;

    int bl, jt, y;
    {
        const int id = blockIdx.x;
        bl = id & (NB - 1);
        const int r = id / NB;
        jt = r & 3;
        y = r >> 2;
    }
    const int bg = b0 + bl;
    const int j0 = jt * 128;
    const size_t abase = (size_t)(bl * 32 + y) * 65536;
    const size_t bbase = (size_t)(bg * 4 + jt) * 65536;

    f32x4 acc[4][4];
    const f32x4 zero = {0.f, 0.f, 0.f, 0.f};
    #pragma unroll
    for (int a = 0; a < 4; ++a)
        #pragma unroll
        for (int b = 0; b < 4; ++b) acc[a][b] = zero;

    for (int kt2 = 0; kt2 < 8; ++kt2) {
        const size_t ab = abase + kt2 * 8192;
        const size_t bb = bbase + kt2 * 8192;
        #pragma unroll
        for (int c = 0; c < 4; ++c) {
            const int s8 = t + c * 256;
            stage16(A1 + ab + s8 * 8, As + s8 * 8);
            stage16(a2t + bb + s8 * 8, Bs + s8 * 8);
        }
        __syncthreads();
        #pragma unroll
        for (int kk2 = 0; kk2 < 2; ++kk2) {
            const int kq = kk2 * 4 + q;
            f16x8 bfr[4];
            #pragma unroll
            for (int nn = 0; nn < 4; ++nn)
                bfr[nn] = *(const f16x8*)(Bs + ((size_t)kq * 128 + wn * 64 + nn * 16 + i15) * 8);
            #pragma unroll
            for (int mt = 0; mt < 4; ++mt) {
                const int m = wm * 64 + mt * 16 + i15;
                f16x8 a = *(const f16x8*)(As + ((size_t)kq * 128 + m) * 8);
                #pragma unroll
                for (int nn = 0; nn < 4; ++nn)
                    acc[mt][nn] = __builtin_amdgcn_mfma_f32_16x16x32_f16(a, bfr[nn], acc[mt][nn], 0, 0, 0);
            }
        }
        __syncthreads();
    }

    // epilogue: thread covers i = y*16 + q*4 + r (4 i), j (4 nn), k = wm*4+mt
    float U4[4];
    float cbias = 0.f;
    #pragma unroll
    for (int k = 0; k < 8; ++k) cbias += U[k] * bvec[k];
    #pragma unroll
    for (int mt = 0; mt < 4; ++mt) U4[mt] = U[wm * 4 + mt];

    float g1v[4][4], s1v[4][4];
    #pragma unroll
    for (int r = 0; r < 4; ++r) {
        const int ig = y * 16 + q * 4 + r;
        const float4 g1 = *(const float4*)(G1 + ((size_t)bg * L_ + ig) * S_ + wm * 4);
        const float4 s1 = *(const float4*)(S1 + ((size_t)bg * L_ + ig) * S_ + wm * 4);
        g1v[r][0] = g1.x; g1v[r][1] = g1.y; g1v[r][2] = g1.z; g1v[r][3] = g1.w;
        s1v[r][0] = s1.x; s1v[r][1] = s1.y; s1v[r][2] = s1.z; s1v[r][3] = s1.w;
    }

    float part[4][4];   // [nn][r]
    #pragma unroll
    for (int nn = 0; nn < 4; ++nn) {
        const int j = j0 + wn * 64 + nn * 16 + i15;
        const float4 g2 = *(const float4*)(G2 + ((size_t)bg * L_ + j) * S_ + wm * 4);
        const float4 s2 = *(const float4*)(S2 + ((size_t)bg * L_ + j) * S_ + wm * 4);
        const float g2p[4] = {g2.x, g2.y, g2.z, g2.w};
        const float s2p[4] = {s2.x, s2.y, s2.z, s2.w};
        #pragma unroll
        for (int r = 0; r < 4; ++r) {
            float p = 0.f;
            #pragma unroll
            for (int mt = 0; mt < 4; ++mt) {
                const float g  = sigm(g1v[r][mt] + g2p[mt]);
                const float si = sigm(s1v[r][mt] + s2p[mt]);
                p += U4[mt] * (acc[mt][nn][r] * g + si * (1.f - g));
            }
            part[nn][r] = p;
        }
    }

    // cross-wave k-half exchange (wm=0 <-> wm=1 partner = t +/- 128)
    float* xb = (float*)lds;                        // 16 KB
    #pragma unroll
    for (int nn = 0; nn < 4; ++nn)
        *(float4*)(xb + t * 16 + nn * 4) = *(const float4*)&part[nn][0];
    __syncthreads();
    if (wm == 0) {
        #pragma unroll
        for (int nn = 0; nn < 4; ++nn) {
            const int j = j0 + wn * 64 + nn * 16 + i15;
            const float4 o = *(const float4*)(xb + (t + 128) * 16 + nn * 4);
            const float op[4] = {o.x, o.y, o.z, o.w};
            #pragma unroll
            for (int r = 0; r < 4; ++r) {
                const int ig = y * 16 + q * 4 + r;
                out[((size_t)bg * L_ + ig) * L_ + j] = sigm(part[nn][r] + op[r] + cbias);
            }
        }
    }
}

// ---------------------------------------------------------------------------
extern "C" void kernel_launch(void* const* d_in, const int* in_sizes, int n_in,
                              void* d_out, int out_size, void* d_ws, size_t ws_size,
                              hipStream_t stream)
{
    const float* arg1 = (const float*)d_in[0];
    const float* arg2 = (const float*)d_in[1];
    const float* Wg   = (const float*)d_in[2];
    const float* Bg   = (const float*)d_in[3];
    const float* Mr   = (const float*)d_in[4];
    const float* V    = (const float*)d_in[5];
    const float* bvec = (const float*)d_in[6];
    const float* U    = (const float*)d_in[7];
    float* out = (float*)d_out;

    char* w = (char*)d_ws;
    size_t off = 0;
    auto nxt = [&](size_t bytes) -> void* {
        void* p = w + off;
        off = (off + bytes + 255) & ~(size_t)255;
        return p;
    };

    _Float16* mrT = (_Float16*)nxt((size_t)S_ * D_ * D_ * 2);
    _Float16* Wt  = (_Float16*)nxt((size_t)2 * 16 * 4 * 16 * 8 * 2);
    float* G1 = (float*)nxt((size_t)B_ * L_ * S_ * 4);
    float* G2 = (float*)nxt((size_t)B_ * L_ * S_ * 4);
    float* S1 = (float*)nxt((size_t)B_ * L_ * S_ * 4);
    float* S2 = (float*)nxt((size_t)B_ * L_ * S_ * 4);
    _Float16* a1h = (_Float16*)nxt((size_t)B_ * L_ * D_ * 2);
    _Float16* a2h = (_Float16*)nxt((size_t)B_ * L_ * D_ * 2);
    const size_t fixed = off;

    const size_t perA1 = (size_t)L_ * S_ * D_ * 2;   // 4.19 MB per batch
    int NB = 8;
    while (NB > 1 && fixed + (size_t)NB * perA1 + 4096 > ws_size) NB >>= 1;
    _Float16* A1 = (_Float16*)nxt((size_t)NB * perA1);

    conv_mrT_kernel<<<dim3(16, 16, 8), 256, 0, stream>>>(Mr, mrT);
    conv_tiled_kernel<<<dim3(512), 256, 0, stream>>>(arg1, a1h);
    conv_tiled_kernel<<<dim3(512), 256, 0, stream>>>(arg2, a2h);
    convW_kernel<<<dim3(64), 256, 0, stream>>>(Wg, V, Wt);
    proj_mfma_kernel<<<dim3(512), 256, 0, stream>>>(a1h, a2h, Wt, Bg, G1, G2, S1, S2);

    for (int b0 = 0; b0 < B_; b0 += NB) {
        gemm_a_kernel<<<dim3(32 * NB * 4), 256, 0, stream>>>(a1h, mrT, A1, b0 * 4, NB * 4);
        gemm_b_kernel<<<dim3(NB * 128), 256, 0, stream>>>(
            A1, a2h, G1, G2, S1, S2, U, bvec, out, b0, NB);
    }
}